// Round 3
// baseline (111.255 us; speedup 1.0000x reference)
//
#include <hip/hip_runtime.h>

// PillarFeatureNet fused, deterministic (no atomics, no memset):
//   A) pfn_stats: per-block 54-moment partials (LDS-staged pillar reads)
//   B) pfn_finalize: parallel partial reduce -> per-channel scale/shift
//   C) pfn_out: wave-per-pillar, LDS-staged points, extrema + BN + relu
// features [K,P,4] f32, num_voxels [K] i32, coors [K,4] i32,
// W [9,64] f32, gamma/beta [64] f32 -> out [K,64] f32.

#define NM 54   // 9 first moments + 45 upper-tri second moments
#define NMP 56  // padded row stride for partials

__device__ __forceinline__ float wave_reduce_sum(float v) {
#pragma unroll
  for (int off = 1; off < 64; off <<= 1) v += __shfl_xor(v, off, 64);
  return v;
}

// Pass A: per-lane moment accumulation over grid-strided pillars,
// wave + block reduce, per-block partial row (deterministic).
__global__ void __launch_bounds__(256) pfn_stats(
    const float4* __restrict__ feat, const int* __restrict__ nvox,
    const int* __restrict__ coors, int K, int P, int nwaves,
    float* __restrict__ partials) {
  __shared__ float4 pts[4][100];
  __shared__ float smred[4][NM];
  const int lane = threadIdx.x & 63;
  const int wid = threadIdx.x >> 6;
  const int gw = (blockIdx.x * blockDim.x + threadIdx.x) >> 6;

  float acc[NM];
#pragma unroll
  for (int i = 0; i < NM; ++i) acc[i] = 0.f;

  for (int k = gw; k < K; k += nwaves) {
    // stage pillar into LDS + per-pillar xyz sums over ALL P points
    float sx = 0.f, sy = 0.f, sz = 0.f;
    for (int p = lane; p < P; p += 64) {
      float4 f = feat[k * P + p];
      pts[wid][p] = f;
      sx += f.x; sy += f.y; sz += f.z;
    }
    sx = wave_reduce_sum(sx);
    sy = wave_reduce_sum(sy);
    sz = wave_reduce_sum(sz);
    const int nv = nvox[k];
    const float inv = 1.f / (float)nv;
    const float mx = sx * inv, my = sy * inv, mz = sz * inv;
    const float cx = (float)coors[k * 4 + 3] * 0.2f + 0.1f;
    const float cy = (float)coors[k * 4 + 2] * 0.2f - 39.9f;

    // moments over valid points only (masked points are exact zeros)
    for (int p = lane; p < nv; p += 64) {
      float4 f = pts[wid][p];
      float ft[9] = {f.x, f.y, f.z, f.w, f.x - mx, f.y - my, f.z - mz,
                     f.x - cx, f.y - cy};
#pragma unroll
      for (int c = 0; c < 9; ++c) acc[c] += ft[c];
      int idx = 9;
#pragma unroll
      for (int c = 0; c < 9; ++c)
#pragma unroll
        for (int c2 = c; c2 < 9; ++c2) {
          acc[idx] += ft[c] * ft[c2];
          ++idx;
        }
    }
  }

#pragma unroll
  for (int i = 0; i < NM; ++i) acc[i] = wave_reduce_sum(acc[i]);
  if (lane == 0) {
#pragma unroll
    for (int i = 0; i < NM; ++i) smred[wid][i] = acc[i];
  }
  __syncthreads();
  const int t = threadIdx.x;
  if (t < NM) {
    partials[blockIdx.x * NMP + t] =
        smred[0][t] + smred[1][t] + smred[2][t] + smred[3][t];
  }
}

// Pass B: reduce per-block partials (224-thread parallel), then
// per-channel scale/shift. One block x 256 threads.
__global__ void __launch_bounds__(256) pfn_finalize(
    const float* __restrict__ partials, int nblocks,
    const float* __restrict__ W, const float* __restrict__ gamma,
    const float* __restrict__ beta, float invN, float* __restrict__ ss) {
  __shared__ float sm[4][NMP];
  __shared__ float msum[NM];
  const int t = threadIdx.x;

  if (t < 4 * NMP) {
    const int m = t % NMP;  // moment (0..55; 54,55 unused)
    const int g = t / NMP;  // row group
    float s = 0.f;
    for (int b = g; b < nblocks; b += 4) s += partials[b * NMP + m];
    sm[g][m] = s;
  }
  __syncthreads();
  if (t < NM) msum[t] = sm[0][t] + sm[1][t] + sm[2][t] + sm[3][t];
  __syncthreads();

  if (t < 64) {
    float wc[9];
#pragma unroll
    for (int c = 0; c < 9; ++c) wc[c] = W[c * 64 + t];

    float mu = 0.f;
#pragma unroll
    for (int c = 0; c < 9; ++c) mu += msum[c] * invN * wc[c];

    float ex2 = 0.f;
    int idx = 9;
#pragma unroll
    for (int c = 0; c < 9; ++c)
#pragma unroll
      for (int c2 = c; c2 < 9; ++c2) {
        float v = msum[idx] * invN * wc[c] * wc[c2];
        ex2 += (c == c2) ? v : 2.f * v;
        ++idx;
      }
    float var = ex2 - mu * mu;
    float scale = gamma[t] * rsqrtf(var + 1e-3f);
    float shift = beta[t] - mu * scale;
    ss[t] = scale;
    ss[64 + t] = shift;
  }
}

// Pass C: wave per pillar, lane = channel. Stage points in LDS (coalesced),
// extrema of bias-free dot over valid points from LDS broadcast reads,
// bias post-hoc, masked points contribute raw 0, BN affine + relu.
__global__ void __launch_bounds__(256) pfn_out(
    const float4* __restrict__ feat, const int* __restrict__ nvox,
    const int* __restrict__ coors, const float* __restrict__ W,
    const float* __restrict__ ss, int K, int P, float* __restrict__ out) {
  __shared__ float4 pts[4][100];
  const int lane = threadIdx.x & 63;
  const int wid = threadIdx.x >> 6;
  const int k = blockIdx.x * 4 + wid;
  if (k >= K) return;

  const float w3 = W[3 * 64 + lane];
  const float w4 = W[4 * 64 + lane], w5 = W[5 * 64 + lane];
  const float w6 = W[6 * 64 + lane], w7 = W[7 * 64 + lane];
  const float w8 = W[8 * 64 + lane];
  const float wxs = W[0 * 64 + lane] + w4 + w7;
  const float wys = W[1 * 64 + lane] + w5 + w8;
  const float wzs = W[2 * 64 + lane] + w6;
  const float scale = ss[lane], shift = ss[64 + lane];

  // stage + per-pillar xyz sums (coalesced float4 loads)
  float sx = 0.f, sy = 0.f, sz = 0.f;
  for (int p = lane; p < P; p += 64) {
    float4 f = feat[k * P + p];
    pts[wid][p] = f;
    sx += f.x; sy += f.y; sz += f.z;
  }
  sx = wave_reduce_sum(sx);
  sy = wave_reduce_sum(sy);
  sz = wave_reduce_sum(sz);
  const int nv = nvox[k];
  const float inv = 1.f / (float)nv;
  const float mx = sx * inv, my = sy * inv, mz = sz * inv;
  const float cx = (float)coors[k * 4 + 3] * 0.2f + 0.1f;
  const float cy = (float)coors[k * 4 + 2] * 0.2f - 39.9f;
  const float bias = -(mx * w4 + my * w5 + mz * w6 + cx * w7 + cy * w8);

  // extrema of bias-free dot product over valid points (LDS broadcast reads)
  float bmax0 = -3e38f, bmin0 = 3e38f, bmax1 = -3e38f, bmin1 = 3e38f;
  int p = 0;
  for (; p + 1 < nv; p += 2) {
    float4 f0 = pts[wid][p];
    float4 f1 = pts[wid][p + 1];
    float b0 = fmaf(f0.x, wxs, fmaf(f0.y, wys, fmaf(f0.z, wzs, f0.w * w3)));
    float b1 = fmaf(f1.x, wxs, fmaf(f1.y, wys, fmaf(f1.z, wzs, f1.w * w3)));
    bmax0 = fmaxf(bmax0, b0); bmin0 = fminf(bmin0, b0);
    bmax1 = fmaxf(bmax1, b1); bmin1 = fminf(bmin1, b1);
  }
  if (p < nv) {
    float4 f0 = pts[wid][p];
    float b0 = fmaf(f0.x, wxs, fmaf(f0.y, wys, fmaf(f0.z, wzs, f0.w * w3)));
    bmax0 = fmaxf(bmax0, b0); bmin0 = fminf(bmin0, b0);
  }
  float vmax = fmaxf(bmax0, bmax1) + bias;
  float vmin = fminf(bmin0, bmin1) + bias;
  if (nv < P) {  // masked points: raw x == 0
    vmax = fmaxf(vmax, 0.f);
    vmin = fminf(vmin, 0.f);
  }
  const float sel = (scale >= 0.f) ? vmax : vmin;
  out[k * 64 + lane] = fmaxf(fmaf(scale, sel, shift), 0.f);
}

extern "C" void kernel_launch(void* const* d_in, const int* in_sizes, int n_in,
                              void* d_out, int out_size, void* d_ws,
                              size_t ws_size, hipStream_t stream) {
  const float4* feat = (const float4*)d_in[0];
  const int* nvox = (const int*)d_in[1];
  const int* coors = (const int*)d_in[2];
  const float* W = (const float*)d_in[3];
  const float* gamma = (const float*)d_in[4];
  const float* beta = (const float*)d_in[5];
  float* out = (float*)d_out;

  const int K = in_sizes[1];
  const int P = in_sizes[0] / (K * 4);

  float* ss = (float*)d_ws;      // [128]: scale, shift
  float* partials = ss + 128;    // [blocksA * NMP]

  // largest power-of-two block count whose partials fit in ws
  int blocksA = 1024;
  while (blocksA > 64 &&
         (size_t)(128 + blocksA * NMP) * sizeof(float) > ws_size)
    blocksA >>= 1;

  pfn_stats<<<blocksA, 256, 0, stream>>>(feat, nvox, coors, K, P, blocksA * 4,
                                         partials);
  pfn_finalize<<<1, 256, 0, stream>>>(partials, blocksA, W, gamma, beta,
                                      1.0f / (float)((long long)K * P), ss);
  pfn_out<<<(K + 3) / 4, 256, 0, stream>>>(feat, nvox, coors, W, ss, K, P, out);
}

// Round 4
// 52.770 us; speedup vs baseline: 2.1083x; 2.1083x over previous
//
#include <hip/hip_runtime.h>

// PillarFeatureNet fused, deterministic (no atomics, no memset):
//   A) pfn_stats: per-block 54-moment partials, moment-major layout
//   B) pfn_finalize: unrolled parallel partial reduce -> scale/shift
//   C) pfn_out: wave-per-pillar, LDS-staged points, sign-folded max + BN + relu
// features [K,P,4] f32, num_voxels [K] i32, coors [K,4] i32,
// W [9,64] f32, gamma/beta [64] f32 -> out [K,64] f32.

#define NM 54  // 9 first moments + 45 upper-tri second moments

__device__ __forceinline__ float wave_reduce_sum(float v) {
#pragma unroll
  for (int off = 1; off < 64; off <<= 1) v += __shfl_xor(v, off, 64);
  return v;
}

// Pass A: per-lane moment accumulation over grid-strided pillars,
// wave + block reduce, per-block partial column (moment-major, deterministic).
__global__ void __launch_bounds__(256) pfn_stats(
    const float4* __restrict__ feat, const int* __restrict__ nvox,
    const int* __restrict__ coors, int K, int P, int nwaves, int nblocks,
    float* __restrict__ partials) {
  __shared__ float4 pts[4][100];
  __shared__ float smred[4][NM];
  const int lane = threadIdx.x & 63;
  const int wid = threadIdx.x >> 6;
  const int gw = (blockIdx.x * blockDim.x + threadIdx.x) >> 6;

  float acc[NM];
#pragma unroll
  for (int i = 0; i < NM; ++i) acc[i] = 0.f;

  for (int k = gw; k < K; k += nwaves) {
    // stage pillar into LDS + xyz sums over ALL P points (ref sums unmasked)
    float sx = 0.f, sy = 0.f, sz = 0.f;
    for (int p = lane; p < P; p += 64) {
      float4 f = feat[(size_t)k * P + p];
      pts[wid][p] = f;
      sx += f.x; sy += f.y; sz += f.z;
    }
    sx = wave_reduce_sum(sx);
    sy = wave_reduce_sum(sy);
    sz = wave_reduce_sum(sz);
    const int nv = nvox[k];
    const float inv = 1.f / (float)nv;
    const float mx = sx * inv, my = sy * inv, mz = sz * inv;
    const float cx = (float)coors[k * 4 + 3] * 0.2f + 0.1f;
    const float cy = (float)coors[k * 4 + 2] * 0.2f - 39.9f;

    // moments over valid points only (masked points are exact zeros)
    for (int p = lane; p < nv; p += 64) {
      float4 f = pts[wid][p];
      float ft[9] = {f.x, f.y, f.z, f.w, f.x - mx, f.y - my, f.z - mz,
                     f.x - cx, f.y - cy};
#pragma unroll
      for (int c = 0; c < 9; ++c) acc[c] += ft[c];
      int idx = 9;
#pragma unroll
      for (int c = 0; c < 9; ++c)
#pragma unroll
        for (int c2 = c; c2 < 9; ++c2) {
          acc[idx] += ft[c] * ft[c2];
          ++idx;
        }
    }
  }

#pragma unroll
  for (int i = 0; i < NM; ++i) acc[i] = wave_reduce_sum(acc[i]);
  if (lane == 0) {
#pragma unroll
    for (int i = 0; i < NM; ++i) smred[wid][i] = acc[i];
  }
  __syncthreads();
  const int t = threadIdx.x;
  if (t < NM) {
    partials[t * nblocks + blockIdx.x] =
        smred[0][t] + smred[1][t] + smred[2][t] + smred[3][t];
  }
}

// Pass B: 4 threads per moment, each sums a contiguous quarter-row with 8
// independent accumulators (loads pipeline), shfl-combine, then scale/shift.
__global__ void __launch_bounds__(256) pfn_finalize(
    const float* __restrict__ partials, int nblocks,
    const float* __restrict__ W, const float* __restrict__ gamma,
    const float* __restrict__ beta, float invN, float* __restrict__ ss) {
  __shared__ float msum[NM];
  const int t = threadIdx.x;
  const int m = t >> 2, j = t & 3;

  if (m < NM) {
    const int chunk = nblocks >> 2;
    const float* row = partials + m * nblocks + j * chunk;
    float a0 = 0.f, a1 = 0.f, a2 = 0.f, a3 = 0.f;
    float a4 = 0.f, a5 = 0.f, a6 = 0.f, a7 = 0.f;
    int b = 0;
    for (; b + 8 <= chunk; b += 8) {
      a0 += row[b];     a1 += row[b + 1]; a2 += row[b + 2]; a3 += row[b + 3];
      a4 += row[b + 4]; a5 += row[b + 5]; a6 += row[b + 6]; a7 += row[b + 7];
    }
    for (; b < chunk; ++b) a0 += row[b];
    float s = ((a0 + a1) + (a2 + a3)) + ((a4 + a5) + (a6 + a7));
    s += __shfl_xor(s, 1, 64);  // partners share m (same wave, low bits)
    s += __shfl_xor(s, 2, 64);
    if (j == 0) msum[m] = s;
  }
  __syncthreads();

  if (t < 64) {
    float wc[9];
#pragma unroll
    for (int c = 0; c < 9; ++c) wc[c] = W[c * 64 + t];

    float mu = 0.f;
#pragma unroll
    for (int c = 0; c < 9; ++c) mu += msum[c] * invN * wc[c];

    float ex2 = 0.f;
    int idx = 9;
#pragma unroll
    for (int c = 0; c < 9; ++c)
#pragma unroll
      for (int c2 = c; c2 < 9; ++c2) {
        float v = msum[idx] * invN * wc[c] * wc[c2];
        ex2 += (c == c2) ? v : 2.f * v;
        ++idx;
      }
    float var = ex2 - mu * mu;
    float scale = gamma[t] * rsqrtf(var + 1e-3f);
    float shift = beta[t] - mu * scale;
    ss[t] = scale;
    ss[64 + t] = shift;
  }
}

// Pass C: wave per pillar, lane = channel. Stage points in LDS (coalesced),
// sign-folded single-extremum over valid points (LDS broadcast reads,
// unroll-4 independent accumulators), bias post-hoc, BN + relu.
__global__ void __launch_bounds__(512) pfn_out(
    const float4* __restrict__ feat, const int* __restrict__ nvox,
    const int* __restrict__ coors, const float* __restrict__ W,
    const float* __restrict__ ss, int K, int P, float* __restrict__ out) {
  __shared__ float4 pts[8][100];
  const int lane = threadIdx.x & 63;
  const int wid = threadIdx.x >> 6;
  const int k = blockIdx.x * 8 + wid;
  if (k >= K) return;

  const float w4 = W[256 + lane], w5 = W[320 + lane], w6 = W[384 + lane];
  const float w7 = W[448 + lane], w8 = W[512 + lane];
  const float scale = ss[lane], shift = ss[64 + lane];
  const float sgn = (scale >= 0.f) ? 1.f : -1.f;
  const float ascale = fabsf(scale);
  // sign-folded weights: max of folded dot == selected extremum of raw dot
  const float wxs = (W[lane] + w4 + w7) * sgn;
  const float wys = (W[64 + lane] + w5 + w8) * sgn;
  const float wzs = (W[128 + lane] + w6) * sgn;
  const float w3s = W[192 + lane] * sgn;

  // stage + per-pillar xyz sums (coalesced float4 loads, all P points)
  float sx = 0.f, sy = 0.f, sz = 0.f;
  for (int p = lane; p < P; p += 64) {
    float4 f = feat[(size_t)k * P + p];
    pts[wid][p] = f;
    sx += f.x; sy += f.y; sz += f.z;
  }
  sx = wave_reduce_sum(sx);
  sy = wave_reduce_sum(sy);
  sz = wave_reduce_sum(sz);
  const int nv = nvox[k];
  const float inv = 1.f / (float)nv;
  const float cx = (float)coors[k * 4 + 3] * 0.2f + 0.1f;
  const float cy = (float)coors[k * 4 + 2] * 0.2f - 39.9f;
  const float biasp =
      -(sx * inv * w4 + sy * inv * w5 + sz * inv * w6 + cx * w7 + cy * w8) * sgn;

  // sign-folded max over valid points, 4 independent accumulators
  float m0 = -3e38f, m1 = -3e38f, m2 = -3e38f, m3 = -3e38f;
  int p = 0;
  for (; p + 4 <= nv; p += 4) {
    float4 f0 = pts[wid][p];
    float4 f1 = pts[wid][p + 1];
    float4 f2 = pts[wid][p + 2];
    float4 f3 = pts[wid][p + 3];
    m0 = fmaxf(m0, fmaf(f0.x, wxs, fmaf(f0.y, wys, fmaf(f0.z, wzs, f0.w * w3s))));
    m1 = fmaxf(m1, fmaf(f1.x, wxs, fmaf(f1.y, wys, fmaf(f1.z, wzs, f1.w * w3s))));
    m2 = fmaxf(m2, fmaf(f2.x, wxs, fmaf(f2.y, wys, fmaf(f2.z, wzs, f2.w * w3s))));
    m3 = fmaxf(m3, fmaf(f3.x, wxs, fmaf(f3.y, wys, fmaf(f3.z, wzs, f3.w * w3s))));
  }
  for (; p < nv; ++p) {
    float4 f0 = pts[wid][p];
    m0 = fmaxf(m0, fmaf(f0.x, wxs, fmaf(f0.y, wys, fmaf(f0.z, wzs, f0.w * w3s))));
  }
  const float bmax = fmaxf(fmaxf(m0, m1), fmaxf(m2, m3));

  float val = fmaf(ascale, bmax + biasp, shift);
  if (nv < P) val = fmaxf(val, shift);  // masked points: x==0 -> BN(0)=shift
  out[(size_t)k * 64 + lane] = fmaxf(val, 0.f);
}

extern "C" void kernel_launch(void* const* d_in, const int* in_sizes, int n_in,
                              void* d_out, int out_size, void* d_ws,
                              size_t ws_size, hipStream_t stream) {
  const float4* feat = (const float4*)d_in[0];
  const int* nvox = (const int*)d_in[1];
  const int* coors = (const int*)d_in[2];
  const float* W = (const float*)d_in[3];
  const float* gamma = (const float*)d_in[4];
  const float* beta = (const float*)d_in[5];
  float* out = (float*)d_out;

  const int K = in_sizes[1];
  const int P = in_sizes[0] / (K * 4);

  float* ss = (float*)d_ws;    // [128]: scale, shift
  float* partials = ss + 128;  // [NM * blocksA], moment-major

  // largest power-of-two block count whose partials fit in ws (prefer 512)
  int blocksA = 512;
  while (blocksA > 64 &&
         (size_t)(128 + NM * blocksA) * sizeof(float) > ws_size)
    blocksA >>= 1;

  pfn_stats<<<blocksA, 256, 0, stream>>>(feat, nvox, coors, K, P, blocksA * 4,
                                         blocksA, partials);
  pfn_finalize<<<1, 256, 0, stream>>>(partials, blocksA, W, gamma, beta,
                                      1.0f / (float)((long long)K * P), ss);
  pfn_out<<<(K + 7) / 8, 512, 0, stream>>>(feat, nvox, coors, W, ss, K, P,
                                           out);
}

// Round 5
// 46.756 us; speedup vs baseline: 2.3795x; 1.1286x over previous
//
#include <hip/hip_runtime.h>

// PillarFeatureNet fused, single feature read:
//  K1 pfn_main: per-pillar raw extrema (max&min, ch-pairs packed f32x2)
//               + global BN moments via Q (raw, pillar-agnostic) and
//               o-cross-terms (per-pillar, lane-parallel). Deterministic
//               per-block partials (no atomics).
//  K2 pfn_finalize: reduce 68 partial rows -> per-channel scale/shift.
//  K3 pfn_apply: elementwise select extremum by sign(scale), BN + relu.
// features [K,P,4] f32, num_voxels [K] i32, coors [K,4] i32,
// W [9,64] f32, gamma/beta [64] f32 -> out [K,64] f32.

typedef float f32x2 __attribute__((ext_vector_type(2)));

#define NQ 14  // 4 raw first + 10 raw second moments (valid points)
#define NO 54  // o-cross-term rows (9 first + 45 second)
#define NP 68  // NQ + NO

__device__ __forceinline__ float wred(float v) {
#pragma unroll
  for (int off = 1; off < 64; off <<= 1) v += __shfl_xor(v, off, 64);
  return v;
}

__global__ void __launch_bounds__(512) pfn_main(
    const float4* __restrict__ feat, const int* __restrict__ nvox,
    const int* __restrict__ coors, const float* __restrict__ W, int K, int P,
    int nwaves, int nblocks, float* __restrict__ partials,
    float4* __restrict__ ext) {
  __shared__ float4 pts[8][102];
  __shared__ float redQ[8][NQ];
  __shared__ float redO[8][NO];
  const int lane = threadIdx.x & 63;
  const int wid = threadIdx.x >> 6;
  const int hl = lane & 31;
  const int p0 = lane >> 5;  // half id: even/odd point

  // decode this lane's o-moment (c,c2) pair (lanes 9..53); lanes 0..8 = first
  int c_i = lane, c2_i = lane;
  if (lane >= 9 && lane < NO) {
    int r = lane - 9, c = 0;
    while (r >= 9 - c) { r -= 9 - c; ++c; }
    c_i = c; c2_i = c + r;
  }
  const int gc = (c_i < 4) ? c_i : (c_i < 7 ? c_i - 4 : c_i - 7);
  const int gc2 = (c2_i < 4) ? c2_i : (c2_i < 7 ? c2_i - 4 : c2_i - 7);

  // W column pairs for channels (2*hl, 2*hl+1)
  const f32x2* W2 = (const f32x2*)W;  // [9][32]
  const f32x2 w4 = W2[4 * 32 + hl], w5 = W2[5 * 32 + hl];
  const f32x2 w6 = W2[6 * 32 + hl], w7 = W2[7 * 32 + hl];
  const f32x2 w8 = W2[8 * 32 + hl];
  const f32x2 wx = W2[0 * 32 + hl] + w4 + w7;
  const f32x2 wy = W2[1 * 32 + hl] + w5 + w8;
  const f32x2 wz = W2[2 * 32 + hl] + w6;
  const f32x2 w3 = W2[3 * 32 + hl];

  // global per-lane accumulators
  float gvx = 0, gvy = 0, gvz = 0, gvw = 0;
  float qxx = 0, qxy = 0, qxz = 0, qxw = 0, qyy = 0;
  float qyz = 0, qyw = 0, qzz = 0, qzw = 0, qww = 0;
  float oacc = 0;

  const int gw = (blockIdx.x * blockDim.x + threadIdx.x) >> 6;
  for (int k = gw; k < K; k += nwaves) {
    const size_t base = (size_t)k * P;
    const int nv = nvox[k];
    float sax = 0, say = 0, saz = 0;          // all-P sums (for mean)
    float svx = 0, svy = 0, svz = 0, svw = 0;  // valid sums (per-pillar)
    for (int p = lane; p < P; p += 64) {
      float4 f = feat[base + p];
      pts[wid][p] = f;
      sax += f.x; say += f.y; saz += f.z;
      if (p < nv) {
        svx += f.x; svy += f.y; svz += f.z; svw += f.w;
        qxx = fmaf(f.x, f.x, qxx); qxy = fmaf(f.x, f.y, qxy);
        qxz = fmaf(f.x, f.z, qxz); qxw = fmaf(f.x, f.w, qxw);
        qyy = fmaf(f.y, f.y, qyy); qyz = fmaf(f.y, f.z, qyz);
        qyw = fmaf(f.y, f.w, qyw); qzz = fmaf(f.z, f.z, qzz);
        qzw = fmaf(f.z, f.w, qzw); qww = fmaf(f.w, f.w, qww);
      }
    }
    // duplicate a valid point into slot nv so the odd tail is harmless
    if ((nv & 1) && nv < P && lane == 0) pts[wid][nv] = pts[wid][0];
    const float rsax = wred(sax), rsay = wred(say), rsaz = wred(saz);
    const float rsvx = wred(svx), rsvy = wred(svy);
    const float rsvz = wred(svz), rsvw = wred(svw);
    gvx += svx; gvy += svy; gvz += svz; gvw += svw;  // pre-reduce partials

    const float nvf = (float)nv, inv = 1.f / nvf;
    const float mx = rsax * inv, my = rsay * inv, mz = rsaz * inv;
    const float cx = (float)coors[k * 4 + 3] * 0.2f + 0.1f;
    const float cy = (float)coors[k * 4 + 2] * 0.2f - 39.9f;

    // o-cross-term accumulation (lane-parallel over 54 moments)
    if (lane < 9) {
      const float oc = (lane == 4) ? -mx : (lane == 5) ? -my
                     : (lane == 6) ? -mz : (lane == 7) ? -cx
                     : (lane == 8) ? -cy : 0.f;
      oacc = fmaf(nvf, oc, oacc);
    } else if (lane < NO) {
      const float oc = (c_i == 4) ? -mx : (c_i == 5) ? -my
                     : (c_i == 6) ? -mz : (c_i == 7) ? -cx
                     : (c_i == 8) ? -cy : 0.f;
      const float oc2 = (c2_i == 4) ? -mx : (c2_i == 5) ? -my
                      : (c2_i == 6) ? -mz : (c2_i == 7) ? -cx
                      : (c2_i == 8) ? -cy : 0.f;
      const float sgc = (gc == 0) ? rsvx : (gc == 1) ? rsvy
                      : (gc == 2) ? rsvz : rsvw;
      const float sgc2 = (gc2 == 0) ? rsvx : (gc2 == 1) ? rsvy
                       : (gc2 == 2) ? rsvz : rsvw;
      oacc += oc * sgc2 + oc2 * sgc + nvf * oc * oc2;
    }

    // extrema: halves process even/odd points, channels packed f32x2
    const f32x2 bias = -(mx * w4 + my * w5 + mz * w6 + cx * w7 + cy * w8);
    f32x2 bm0 = {-3e38f, -3e38f}, bm1 = {-3e38f, -3e38f};
    f32x2 bn0 = {3e38f, 3e38f}, bn1 = {3e38f, 3e38f};
    const int nvv = nv + (nv & 1);
    int p = 0;
    for (; p + 4 <= nvv; p += 4) {
      float4 fa = pts[wid][p + p0];
      float4 fb = pts[wid][p + 2 + p0];
      f32x2 ba = wx * fa.x + wy * fa.y + wz * fa.z + w3 * fa.w;
      f32x2 bb = wx * fb.x + wy * fb.y + wz * fb.z + w3 * fb.w;
      bm0.x = fmaxf(bm0.x, ba.x); bm0.y = fmaxf(bm0.y, ba.y);
      bn0.x = fminf(bn0.x, ba.x); bn0.y = fminf(bn0.y, ba.y);
      bm1.x = fmaxf(bm1.x, bb.x); bm1.y = fmaxf(bm1.y, bb.y);
      bn1.x = fminf(bn1.x, bb.x); bn1.y = fminf(bn1.y, bb.y);
    }
    for (; p < nvv; p += 2) {
      float4 fa = pts[wid][p + p0];
      f32x2 ba = wx * fa.x + wy * fa.y + wz * fa.z + w3 * fa.w;
      bm0.x = fmaxf(bm0.x, ba.x); bm0.y = fmaxf(bm0.y, ba.y);
      bn0.x = fminf(bn0.x, ba.x); bn0.y = fminf(bn0.y, ba.y);
    }
    f32x2 bm, bn;
    bm.x = fmaxf(bm0.x, bm1.x); bm.y = fmaxf(bm0.y, bm1.y);
    bn.x = fminf(bn0.x, bn1.x); bn.y = fminf(bn0.y, bn1.y);
    bm.x = fmaxf(bm.x, __shfl_xor(bm.x, 32, 64));
    bm.y = fmaxf(bm.y, __shfl_xor(bm.y, 32, 64));
    bn.x = fminf(bn.x, __shfl_xor(bn.x, 32, 64));
    bn.y = fminf(bn.y, __shfl_xor(bn.y, 32, 64));
    f32x2 vmax = bm + bias, vmin = bn + bias;
    if (nv < P) {  // masked rows contribute raw x == 0
      vmax.x = fmaxf(vmax.x, 0.f); vmax.y = fmaxf(vmax.y, 0.f);
      vmin.x = fminf(vmin.x, 0.f); vmin.y = fminf(vmin.y, 0.f);
    }
    if (lane < 32) {
      float4 e; e.x = vmax.x; e.y = vmax.y; e.z = vmin.x; e.w = vmin.y;
      ext[(size_t)k * 32 + hl] = e;
    }
  }

  // block-level partial reduction (deterministic)
  float qa[NQ] = {gvx, gvy, gvz, gvw, qxx, qxy, qxz,
                  qxw, qyy, qyz, qyw, qzz, qzw, qww};
#pragma unroll
  for (int i = 0; i < NQ; ++i) qa[i] = wred(qa[i]);
  if (lane == 0) {
#pragma unroll
    for (int i = 0; i < NQ; ++i) redQ[wid][i] = qa[i];
  }
  if (lane < NO) redO[wid][lane] = oacc;
  __syncthreads();
  const int t = threadIdx.x;
  if (t < NQ) {
    float s = 0;
#pragma unroll
    for (int w = 0; w < 8; ++w) s += redQ[w][t];
    partials[t * nblocks + blockIdx.x] = s;
  }
  if (t >= 64 && t < 64 + NO) {
    const int m = t - 64;
    float s = 0;
#pragma unroll
    for (int w = 0; w < 8; ++w) s += redO[w][m];
    partials[(NQ + m) * nblocks + blockIdx.x] = s;
  }
}

// K2: reduce 68 partial rows (4 threads/row, 8-way ILP), assemble the 54
// augmented-feature moments, then per-channel scale/shift.
__global__ void __launch_bounds__(512) pfn_finalize(
    const float* __restrict__ partials, int nblocks,
    const float* __restrict__ W, const float* __restrict__ gamma,
    const float* __restrict__ beta, float invN, float* __restrict__ ss) {
  __shared__ float msum[NP];
  __shared__ float m54[NO];
  const int t = threadIdx.x;
  const int m = t >> 2, j = t & 3;
  if (m < NP) {
    const int chunk = nblocks >> 2;
    const float* row = partials + m * nblocks + j * chunk;
    float a0 = 0, a1 = 0, a2 = 0, a3 = 0, a4 = 0, a5 = 0, a6 = 0, a7 = 0;
    int b = 0;
    for (; b + 8 <= chunk; b += 8) {
      a0 += row[b];     a1 += row[b + 1]; a2 += row[b + 2]; a3 += row[b + 3];
      a4 += row[b + 4]; a5 += row[b + 5]; a6 += row[b + 6]; a7 += row[b + 7];
    }
    for (; b < chunk; ++b) a0 += row[b];
    float s = ((a0 + a1) + (a2 + a3)) + ((a4 + a5) + (a6 + a7));
    s += __shfl_xor(s, 1, 64);
    s += __shfl_xor(s, 2, 64);
    if (j == 0) msum[m] = s;
  }
  __syncthreads();
  if (t < NO) {
    float v;
    if (t < 9) {
      const int g = (t < 4) ? t : (t < 7 ? t - 4 : t - 7);
      v = msum[g] + msum[NQ + t];
    } else {
      int r = t - 9, c = 0;
      while (r >= 9 - c) { r -= 9 - c; ++c; }
      const int c2 = c + r;
      const int a = (c < 4) ? c : (c < 7 ? c - 4 : c - 7);
      const int b2 = (c2 < 4) ? c2 : (c2 < 7 ? c2 - 4 : c2 - 7);
      const int lo = a < b2 ? a : b2, hi = a < b2 ? b2 : a;
      const int qi = lo * (9 - lo) / 2 + (hi - lo);
      v = msum[4 + qi] + msum[NQ + t];
    }
    m54[t] = v;
  }
  __syncthreads();
  if (t < 64) {
    float wc[9];
#pragma unroll
    for (int c = 0; c < 9; ++c) wc[c] = W[c * 64 + t];
    float mu = 0.f;
#pragma unroll
    for (int c = 0; c < 9; ++c) mu += m54[c] * invN * wc[c];
    float ex2 = 0.f;
    int idx = 9;
#pragma unroll
    for (int c = 0; c < 9; ++c)
#pragma unroll
      for (int c2 = c; c2 < 9; ++c2) {
        float v = m54[idx] * invN * wc[c] * wc[c2];
        ex2 += (c == c2) ? v : 2.f * v;
        ++idx;
      }
    const float var = ex2 - mu * mu;
    const float scale = gamma[t] * rsqrtf(var + 1e-3f);
    ss[t] = scale;
    ss[64 + t] = beta[t] - mu * scale;
  }
}

// K3: elementwise apply — pick extremum by sign(scale), BN affine + relu.
__global__ void __launch_bounds__(256) pfn_apply(
    const float4* __restrict__ ext, const float* __restrict__ ss, int n,
    f32x2* __restrict__ out) {
  const int t = blockIdx.x * 256 + threadIdx.x;
  if (t >= n) return;
  const int l = t & 31;
  const float4 e = ext[t];
  const f32x2 sc = ((const f32x2*)ss)[l];
  const f32x2 sh = ((const f32x2*)(ss + 64))[l];
  const float v0 = (sc.x >= 0.f) ? e.x : e.z;
  const float v1 = (sc.y >= 0.f) ? e.y : e.w;
  f32x2 o;
  o.x = fmaxf(fmaf(sc.x, v0, sh.x), 0.f);
  o.y = fmaxf(fmaf(sc.y, v1, sh.y), 0.f);
  out[t] = o;
}

extern "C" void kernel_launch(void* const* d_in, const int* in_sizes, int n_in,
                              void* d_out, int out_size, void* d_ws,
                              size_t ws_size, hipStream_t stream) {
  const float4* feat = (const float4*)d_in[0];
  const int* nvox = (const int*)d_in[1];
  const int* coors = (const int*)d_in[2];
  const float* W = (const float*)d_in[3];
  const float* gamma = (const float*)d_in[4];
  const float* beta = (const float*)d_in[5];
  float* out = (float*)d_out;

  const int K = in_sizes[1];
  const int P = in_sizes[0] / (K * 4);

  float* ss = (float*)d_ws;    // [128]: scale, shift
  float* partials = ss + 128;  // [NP * nblk]
  const int nblk = 512;        // ws is ~256 MiB; 10.4 MB total fits easily
  float4* ext = (float4*)(partials + NP * nblk);  // [K*32] float4, 16B-aligned

  pfn_main<<<nblk, 512, 0, stream>>>(feat, nvox, coors, W, K, P, nblk * 8,
                                     nblk, partials, ext);
  pfn_finalize<<<1, 512, 0, stream>>>(partials, nblk, W, gamma, beta,
                                      1.0f / (float)((long long)K * P), ss);
  const int n3 = K * 32;
  pfn_apply<<<(n3 + 255) / 256, 256, 0, stream>>>(ext, ss, n3, (f32x2*)out);
}